// Round 1
// 941.268 us; speedup vs baseline: 1.2514x; 1.2514x over previous
//
#include <hip/hip_runtime.h>
#include <cstdint>
#include <cstddef>

// Problem constants
#define BB   128
#define DD   768
#define LL   131072
#define NBL  512
#define WDC  1e-4f

typedef __attribute__((ext_vector_type(8))) short bf16x8;
typedef __attribute__((ext_vector_type(4))) float f32x4;

__device__ __forceinline__ unsigned short f2bf(float f) {
  union { float f; unsigned u; } v; v.f = f;
  unsigned r = v.u + 0x7fffu + ((v.u >> 16) & 1u);   // RNE
  return (unsigned short)(r >> 16);
}
__device__ __forceinline__ float bf2f(unsigned short h) {
  union { unsigned u; float f; } v; v.u = ((unsigned)h) << 16;
  return v.f;
}
// async global->LDS, 16B per lane. LDS dest is wave-uniform base + lane*16.
__device__ __forceinline__ void gld16(const void* g, void* l) {
  __builtin_amdgcn_global_load_lds(
      (const __attribute__((address_space(1))) unsigned int*)g,
      (__attribute__((address_space(3))) unsigned int*)l, 16, 0, 0);
}

// ---------------------------------------------------------------------------
// k0_wprep: W fp32 -> bf16 in [l][d] (Wbl) and [d][l] (Wdl) layouts.
// Also (blocks < 384): E fp32 -> bf16 in [b][d] and [d][b]; zero grad.
// Pure-BW kernel: reads 403 MB, writes 402 MB.
// ---------------------------------------------------------------------------
__global__ __launch_bounds__(256) void k0_wprep(const float* __restrict__ E,
                                                const float* __restrict__ W,
                                                float* __restrict__ grad,
                                                unsigned short* __restrict__ Ebd,
                                                unsigned short* __restrict__ Edb,
                                                unsigned short* __restrict__ Wbl,
                                                unsigned short* __restrict__ Wdl) {
  __shared__ __align__(16) unsigned short T[128 * 136];
  const int tid = threadIdx.x;
  const int bx  = blockIdx.x;

  if (bx < 384) {                       // E prep + grad zero (98304 elems)
    int i = bx * 256 + tid;
    float v = E[i];
    unsigned short b = f2bf(v);
    Ebd[i] = b;
    int bb = i / DD, d = i - bb * DD;
    Edb[d * BB + bb] = b;
    grad[i] = 0.0f;
  }

  const int l0 = bx * 128;              // 1024 blocks cover L
  for (int dc = 0; dc < 6; ++dc) {
    // read fp32 tile 128l x 128d, convert, write Wbl + LDS T
    #pragma unroll
    for (int p = 0; p < 16; ++p) {
      int idx = tid + p * 256;                 // 0..4095
      int row = idx >> 5, col4 = (idx & 31) * 4;
      float4 v = *reinterpret_cast<const float4*>(
          &W[(size_t)(l0 + row) * DD + dc * 128 + col4]);
      ushort4 b4;
      b4.x = f2bf(v.x); b4.y = f2bf(v.y); b4.z = f2bf(v.z); b4.w = f2bf(v.w);
      *reinterpret_cast<ushort4*>(&Wbl[(size_t)(l0 + row) * DD + dc * 128 + col4]) = b4;
      *reinterpret_cast<ushort4*>(&T[row * 136 + col4]) = b4;
    }
    __syncthreads();
    // transpose out of LDS -> Wdl[d][l] (16B coalesced stores)
    #pragma unroll
    for (int p = 0; p < 8; ++p) {
      int odx = tid + p * 256;                 // 0..2047
      int drow = odx >> 4, l8 = (odx & 15) * 8;
      __align__(16) unsigned short tmp[8];
      #pragma unroll
      for (int t = 0; t < 8; ++t) tmp[t] = T[(l8 + t) * 136 + drow];
      *reinterpret_cast<uint4*>(&Wdl[(size_t)(dc * 128 + drow) * LL + l0 + l8]) =
          *reinterpret_cast<const uint4*>(tmp);
    }
    __syncthreads();
  }
}

// ---------------------------------------------------------------------------
// k1_fused: per 128-l chunk:
//   (1) logits = sigmoid(E @ W^T) via double-buffered global_load_lds GEMM
//   (2) label scatter (set semantics) in LDS
//   (3) write P [b][l] once (for k2_grad)
//   (4) wgrad = P^T @ E per 128-d slice (P from LDS regs, E^T L3-hot)
//   (5) fused newW = (1-lr*wd)*W - lr*wgrad  (W bf16, L2-hot)
// ---------------------------------------------------------------------------
__global__ __launch_bounds__(256, 2) void k1_fused(
    const unsigned short* __restrict__ Wbl,   // bf16 [L][D]
    const unsigned short* __restrict__ Ebd,   // bf16 [B][D]
    const unsigned short* __restrict__ Edb,   // bf16 [D][B]
    const int* __restrict__ labels_raw,
    const float* __restrict__ lr_p,
    unsigned short* __restrict__ Pbl,         // bf16 [B][L]
    float* __restrict__ newW) {
  // U layout: logits phase = dbuf {Ea[128][64], Wa[128][64]} x2 (64 KB)
  //           post-logits  = Pt[128][136] (34816) | Et[128][128] @34816 (32768)
  //           slice loop   = Wu[128][128] @0 (Pt dead after pa-frag loads)
  __shared__ __align__(16) char U[69632];
  __shared__ int lrows[NBL], lcols[NBL];
  __shared__ int modeSh;

  const int tid  = threadIdx.x;
  const int lane = tid & 63;
  const int wave = tid >> 6;
  const int wm = wave & 1, wn = wave >> 1;
  const int q = lane >> 4, c = lane & 15;
  const int l0 = blockIdx.x * 128;
  const float lr = lr_p[0];
  const float decay = 1.0f - lr * WDC;

  // ---- label decode (int32 pairs OR int64 pairs), rawbuf aliases U
  {
    int* rawbuf = (int*)U;
    #pragma unroll
    for (int p = 0; p < 4; ++p) rawbuf[tid + p * 256] = labels_raw[tid + p * 256];
    if (tid == 0) modeSh = 0;
    __syncthreads();
    int o = 0;
    #pragma unroll
    for (int p = 0; p < 2; ++p) o |= rawbuf[(tid + p * 256) * 2 + 1];
    if (o) atomicOr(&modeSh, 1);
    __syncthreads();
    const int is32 = modeSh;
    #pragma unroll
    for (int p = 0; p < 2; ++p) {
      int i = tid + p * 256;
      if (is32) { lrows[i] = rawbuf[2 * i];     lcols[i] = rawbuf[2 * i + 1]; }
      else      { lrows[i] = labels_raw[4 * i]; lcols[i] = labels_raw[4 * i + 2]; }
    }
    __syncthreads();
  }

  // ---- logits GEMM: 128(b) x 128(l), K=768, BK=64, double-buffered
  f32x4 acc[4][4];
  #pragma unroll
  for (int i = 0; i < 4; ++i)
    #pragma unroll
    for (int j = 0; j < 4; ++j) acc[i][j] = 0.0f;

  auto stage_logits = [&](int t, int buf) {
    unsigned short* Ea = (unsigned short*)(U + buf * 32768);
    unsigned short* Wa = Ea + 8192;
    const int k0 = t * 64;
    const int r8 = lane >> 3, c8 = (lane & 7) * 8;
    #pragma unroll
    for (int p = 0; p < 4; ++p) {
      int chunk = wave * 4 + p;
      int row = chunk * 8 + r8;
      gld16(Ebd + (size_t)row * DD + k0 + c8, Ea + chunk * 512);
    }
    #pragma unroll
    for (int p = 0; p < 4; ++p) {
      int chunk = wave * 4 + p;
      int row = chunk * 8 + r8;
      gld16(Wbl + (size_t)(l0 + row) * DD + k0 + c8, Wa + chunk * 512);
    }
  };

  stage_logits(0, 0);
  __syncthreads();
  for (int t = 0; t < 12; ++t) {
    if (t < 11) stage_logits(t + 1, (t + 1) & 1);   // prefetch next tile
    const unsigned short* Ea = (const unsigned short*)(U + (t & 1) * 32768);
    const unsigned short* Wa = Ea + 8192;
    #pragma unroll
    for (int ks = 0; ks < 64; ks += 32) {
      bf16x8 af[4], bfr[4];
      #pragma unroll
      for (int i = 0; i < 4; ++i)
        af[i] = *reinterpret_cast<const bf16x8*>(&Ea[(wm * 64 + i * 16 + c) * 64 + ks + q * 8]);
      #pragma unroll
      for (int j = 0; j < 4; ++j)
        bfr[j] = *reinterpret_cast<const bf16x8*>(&Wa[(wn * 64 + j * 16 + c) * 64 + ks + q * 8]);
      #pragma unroll
      for (int i = 0; i < 4; ++i)
        #pragma unroll
        for (int j = 0; j < 4; ++j)
          acc[i][j] = __builtin_amdgcn_mfma_f32_16x16x32_bf16(af[i], bfr[j], acc[i][j], 0, 0, 0);
    }
    __syncthreads();   // drains prefetch vmcnt + protects buffer reuse
  }

  // ---- epilogue: sigmoid -> Pt
  unsigned short* Pt = (unsigned short*)U;   // [128][136]
  #pragma unroll
  for (int i = 0; i < 4; ++i)
    #pragma unroll
    for (int j = 0; j < 4; ++j)
      #pragma unroll
      for (int r = 0; r < 4; ++r) {
        int b_loc = wm * 64 + i * 16 + q * 4 + r;
        int l_loc = wn * 64 + j * 16 + c;
        float z = acc[i][j][r];
        float pv = 1.0f / (1.0f + __expf(-z));
        Pt[b_loc * 136 + l_loc] = f2bf(pv);
      }
  __syncthreads();

  // ---- scatter: set p[row,col] = p - 1 (idempotent under duplicates)
  float sval[2]; int sact[2], srow[2], scol[2];
  #pragma unroll
  for (int s = 0; s < 2; ++s) {
    int i = tid + s * 256;
    sact[s] = 0;
    int col = lcols[i], row = lrows[i];
    if (col >= l0 && col < l0 + 128) {
      sact[s] = 1; srow[s] = row & 127; scol[s] = col - l0;
      sval[s] = bf2f(Pt[srow[s] * 136 + scol[s]]);
    }
  }
  __syncthreads();
  #pragma unroll
  for (int s = 0; s < 2; ++s)
    if (sact[s]) Pt[srow[s] * 136 + scol[s]] = f2bf(sval[s] - 1.0f);
  __syncthreads();

  // ---- write P [b][l] (16B stores) for k2_grad
  #pragma unroll
  for (int p = 0; p < 8; ++p) {
    int idx = tid + p * 256;
    int row = idx >> 4, col8 = (idx & 15) * 8;
    *reinterpret_cast<uint4*>(&Pbl[(size_t)row * LL + l0 + col8]) =
        *reinterpret_cast<const uint4*>(&Pt[row * 136 + col8]);
  }

  // ---- wgrad A fragments (P^T, k=b): held in regs across all 6 d-slices
  bf16x8 pa[4][4];
  #pragma unroll
  for (int i = 0; i < 4; ++i)
    #pragma unroll
    for (int k4 = 0; k4 < 4; ++k4) {
      __align__(16) unsigned short tmp[8];
      #pragma unroll
      for (int e = 0; e < 8; ++e)
        tmp[e] = Pt[(k4 * 32 + q * 8 + e) * 136 + wm * 64 + i * 16 + c];
      pa[i][k4] = *reinterpret_cast<const bf16x8*>(tmp);
    }
  __syncthreads();   // Pt dead; Wu may reuse its region

  // ---- per-d-slice: wgrad GEMM (m=l, n=d, k=b) + fused newW
  unsigned short* Wu = (unsigned short*)U;             // [128 l][128 d]
  unsigned short* Et = (unsigned short*)(U + 34816);   // [128 d][128 b]
  for (int ds = 0; ds < 6; ++ds) {
    #pragma unroll
    for (int p = 0; p < 8; ++p) {        // E^T slice (contiguous, L3-hot)
      int chunk = wave * 8 + p;
      gld16(Edb + ds * 16384 + chunk * 512 + lane * 8, Et + chunk * 512);
    }
    #pragma unroll
    for (int p = 0; p < 8; ++p) {        // W tile for update (L2-hot)
      int chunk = wave * 8 + p;
      int row = chunk * 4 + (lane >> 4);
      gld16(Wbl + (size_t)(l0 + row) * DD + ds * 128 + (lane & 15) * 8,
            Wu + chunk * 512);
    }
    __syncthreads();

    f32x4 wacc[4][4];
    #pragma unroll
    for (int i = 0; i < 4; ++i)
      #pragma unroll
      for (int j = 0; j < 4; ++j) wacc[i][j] = 0.0f;

    #pragma unroll
    for (int k4 = 0; k4 < 4; ++k4) {
      bf16x8 eb[4];
      #pragma unroll
      for (int j = 0; j < 4; ++j)
        eb[j] = *reinterpret_cast<const bf16x8*>(
            &Et[(wn * 64 + j * 16 + c) * 128 + k4 * 32 + q * 8]);
      #pragma unroll
      for (int i = 0; i < 4; ++i)
        #pragma unroll
        for (int j = 0; j < 4; ++j)
          wacc[i][j] = __builtin_amdgcn_mfma_f32_16x16x32_bf16(pa[i][k4], eb[j], wacc[i][j], 0, 0, 0);
    }

    // fused update: newW = decay*W - lr*wgrad  (W from LDS bf16)
    #pragma unroll
    for (int i = 0; i < 4; ++i)
      #pragma unroll
      for (int j = 0; j < 4; ++j)
        #pragma unroll
        for (int r = 0; r < 4; ++r) {
          int lrow = wm * 64 + i * 16 + q * 4 + r;
          int dcol = wn * 64 + j * 16 + c;
          float w = bf2f(Wu[lrow * 128 + dcol]);
          newW[(size_t)(l0 + lrow) * DD + ds * 128 + dcol] =
              decay * w - lr * wacc[i][j][r];
        }
    __syncthreads();
  }
}

// ---------------------------------------------------------------------------
// k2_grad: grad[b][d] += sum_l P[b][l] * W[l][d].  Split-K: grid (6 dslice,
// 64 l-chunks of 2048). Both operands linear bf16 staged via global_load_lds,
// 2-phase pipelined. 6.3M fp32 atomics total.
// ---------------------------------------------------------------------------
__global__ __launch_bounds__(256, 2) void k2_grad(
    const unsigned short* __restrict__ Pbl,   // bf16 [B][L]
    const unsigned short* __restrict__ Wdl,   // bf16 [D][L]
    float* __restrict__ grad) {
  __shared__ __align__(16) char U2[65536];    // 2 x (Pa 16K + Wt 16K)
  const int tid  = threadIdx.x;
  const int lane = tid & 63;
  const int wave = tid >> 6;
  const int wm = wave & 1, wn = wave >> 1;
  const int q = lane >> 4, c = lane & 15;
  const int ds0 = blockIdx.x * 128;
  const size_t lbase = (size_t)blockIdx.y * 2048;

  auto stage = [&](int it, int buf) {
    unsigned short* Pa = (unsigned short*)(U2 + buf * 32768);
    unsigned short* Wt = Pa + 8192;
    const size_t lt = lbase + (size_t)it * 64;
    const int r8 = lane >> 3, c8 = (lane & 7) * 8;
    #pragma unroll
    for (int p = 0; p < 4; ++p) {
      int chunk = wave * 4 + p;
      int row = chunk * 8 + r8;
      gld16(Pbl + (size_t)row * LL + lt + c8, Pa + chunk * 512);
    }
    #pragma unroll
    for (int p = 0; p < 4; ++p) {
      int chunk = wave * 4 + p;
      int row = chunk * 8 + r8;
      gld16(Wdl + (size_t)(ds0 + row) * LL + lt + c8, Wt + chunk * 512);
    }
  };

  f32x4 gacc[4][4];
  #pragma unroll
  for (int i = 0; i < 4; ++i)
    #pragma unroll
    for (int j = 0; j < 4; ++j) gacc[i][j] = 0.0f;

  stage(0, 0);
  __syncthreads();
  for (int it = 0; it < 32; ++it) {
    if (it < 31) stage(it + 1, (it + 1) & 1);
    const unsigned short* Pa = (const unsigned short*)(U2 + (it & 1) * 32768);
    const unsigned short* Wt = Pa + 8192;
    #pragma unroll
    for (int ks = 0; ks < 64; ks += 32) {
      bf16x8 af[4], bfr[4];
      #pragma unroll
      for (int i = 0; i < 4; ++i)
        af[i] = *reinterpret_cast<const bf16x8*>(&Pa[(wm * 64 + i * 16 + c) * 64 + ks + q * 8]);
      #pragma unroll
      for (int j = 0; j < 4; ++j)
        bfr[j] = *reinterpret_cast<const bf16x8*>(&Wt[(wn * 64 + j * 16 + c) * 64 + ks + q * 8]);
      #pragma unroll
      for (int i = 0; i < 4; ++i)
        #pragma unroll
        for (int j = 0; j < 4; ++j)
          gacc[i][j] = __builtin_amdgcn_mfma_f32_16x16x32_bf16(af[i], bfr[j], gacc[i][j], 0, 0, 0);
    }
    __syncthreads();
  }

  // split-K reduction via device-scope atomics
  #pragma unroll
  for (int i = 0; i < 4; ++i)
    #pragma unroll
    for (int j = 0; j < 4; ++j)
      #pragma unroll
      for (int r = 0; r < 4; ++r) {
        int brow = wm * 64 + i * 16 + q * 4 + r;
        int dcol = wn * 64 + j * 16 + c;
        atomicAdd(&grad[brow * DD + ds0 + dcol], gacc[i][j][r]);
      }
}

// ---------------------------------------------------------------------------
extern "C" void kernel_launch(void* const* d_in, const int* in_sizes, int n_in,
                              void* d_out, int out_size, void* d_ws, size_t ws_size,
                              hipStream_t stream) {
  const float* embed  = (const float*)d_in[0];   // 128*768
  const float* W      = (const float*)d_in[1];   // 131072*768
  const int*   labels = (const int*)d_in[2];     // 512*2 (int32 or int64)
  const float* lr_p   = (const float*)d_in[3];   // 1

  float* grad = (float*)d_out;                   // 98304
  float* newW = grad + (size_t)BB * DD;          // 131072*768

  unsigned short* Ebd = (unsigned short*)d_ws;       // E bf16 [b][d]   196,608 B
  unsigned short* Edb = Ebd + (size_t)BB * DD;       // E bf16 [d][b]   196,608 B
  unsigned short* Pbl = Edb + (size_t)BB * DD;       // P bf16 [b][l]    33.6 MB
  unsigned short* Wbl = Pbl + (size_t)BB * LL;       // W bf16 [l][d]   201.3 MB
  unsigned short* Wdl = Wbl + (size_t)LL * DD;       // W bf16 [d][l]   201.3 MB
  // ws bytes needed: 436,600,832

  k0_wprep<<<1024, 256, 0, stream>>>(embed, W, grad, Ebd, Edb, Wbl, Wdl);
  k1_fused<<<1024, 256, 0, stream>>>(Wbl, Ebd, Edb, labels, lr_p, Pbl, newW);
  k2_grad<<<dim3(6, 64), 256, 0, stream>>>(Pbl, Wdl, grad);
}